// Round 11
// baseline (109.758 us; speedup 1.0000x reference)
//
#include <hip/hip_runtime.h>
#include <hip/hip_bf16.h>
#include <hip/hip_fp16.h>

// MiniBatchDiscrimination: out = concat([x, sum_b2 exp(-L1(act_b, act_b2))], axis=1)
// B=512, F=512, K=50, D=16.  act = x @ W : (512, 800).
// Round 11: SINGLE dispatch, group-local producer/consumer sync.
//  - Producer: block bid makes GEMM tile (m=bid&31, n=bid>>5) -- R10's exact
//    decomposition (full 800-block parallelism), f16 act store.
//  - Group locality: consumer (k=bid>>4, chunk=bid&15) needs act cols
//    [16k,+16) which lie inside col-tile n=bid>>5 -- produced by bid's own
//    aligned 32-block group [32n, 32n+32). Groups are self-sufficient =>
//    deadlock-free at any residency; spin lasts only intra-group skew.
//  - Sync protocol: exactly R8's silicon-validated sequence (syncthreads ->
//    release-fence(system) -> system atomicAdd(done[n]); bounded throttled
//    spin -> acquire-fence). Epoch from monotonic ticket (800 draws/call,
//    pigeonhole-exact, no resets; graph-replay and rocprof-rerun safe).

#define B_ROWS 512
#define F_IN   512
#define NK     50
#define DK     16
#define N_COLS (NK * DK)      // 800
#define OUT_COLS (F_IN + NK)  // 562
#define NBLOCKS 800

#if __has_builtin(__builtin_amdgcn_exp2f)
#define EXP2F __builtin_amdgcn_exp2f
#else
#define EXP2F exp2f
#endif

typedef __attribute__((ext_vector_type(8))) short bf16x8;
typedef __attribute__((ext_vector_type(4))) float f32x4;

__device__ unsigned long long g_ticket = 0;      // monotonic across calls
__device__ unsigned long long g_done[25] = {0};  // +32 per col-tile per call

__device__ __forceinline__ short bfs(float f) {
    __hip_bfloat16 h = __float2bfloat16(f);   // RNE; pairs fuse to v_cvt_pk_bf16_f32
    return *reinterpret_cast<short*>(&h);
}

__global__ __launch_bounds__(256) void fused_kernel(const float* __restrict__ x,
                                                    const float* __restrict__ W,
                                                    __half* __restrict__ act_h,
                                                    float* __restrict__ out) {
    __shared__ float4 Sh[1024];   // 16 KB: produce-phase red (8 KB) / consume-phase Ah4 (16 KB)

    const int bid = blockIdx.x;   // 0..799
    const int tid = threadIdx.x;  // 0..255
    const int wave = tid >> 6, l = tid & 63;
    const int rc = l & 15, kg = l >> 4;

    // epoch ticket: exactly one draw per block per call
    unsigned long long target = 0;
    if (tid == 0) {
        unsigned long long tk = __hip_atomic_fetch_add(&g_ticket, 1ULL,
                                    __ATOMIC_RELAXED, __HIP_MEMORY_SCOPE_SYSTEM);
        target = 32ULL * (tk / NBLOCKS + 1ULL);
    }

    // ---------------- x passthrough copy (blocks 0..127) ----------------
    if (bid < 128) {
        #pragma unroll
        for (int i = 0; i < 2; ++i) {
            int gid = bid * 512 + i * 256 + tid;    // 0..65535
            int row = gid >> 7, c4 = gid & 127;
            float4 v = ((const float4*)x)[gid];
            float* o = out + row * OUT_COLS + c4 * 4;   // 8B-aligned (562 even)
            *(float2*)o = make_float2(v.x, v.y);
            *(float2*)(o + 2) = make_float2(v.z, v.w);
        }
    }

    // ---------------- produce: GEMM tile (m=bid&31, n=bid>>5), K split over 4 waves ----
    // A frag: lane l holds x[mBase + (l&15)][kOff + 8*(l>>4) + j]
    // B frag: lane l holds W[kOff + 8*(l>>4) + j][nBase + fr*16 + (l&15)]
    // C/D:    col = l&15, row = (l>>4)*4 + reg   [m89 verified]
    {
        float* red = (float*)Sh;   // 8 KB: [wave][lane][8]
        const int mBase = (bid & 31) * 16;
        const int nBase = (bid >> 5) * 32;

        const float* pa = x + (mBase + rc) * F_IN + wave * 128 + kg * 8;
        const float* pb = W + (wave * 128 + kg * 8) * N_COLS + nBase + rc;

        f32x4 acc0 = {0.f, 0.f, 0.f, 0.f};
        f32x4 acc1 = {0.f, 0.f, 0.f, 0.f};

        #pragma unroll
        for (int ks = 0; ks < 4; ++ks) {
            float4 a0 = *(const float4*)(pa + ks * 32);
            float4 a1 = *(const float4*)(pa + ks * 32 + 4);
            bf16x8 a;
            a[0] = bfs(a0.x); a[1] = bfs(a0.y); a[2] = bfs(a0.z); a[3] = bfs(a0.w);
            a[4] = bfs(a1.x); a[5] = bfs(a1.y); a[6] = bfs(a1.z); a[7] = bfs(a1.w);

            const float* pk = pb + (ks * 32) * N_COLS;
            bf16x8 b0, b1;
            #pragma unroll
            for (int j = 0; j < 8; ++j) {
                b0[j] = bfs(pk[j * N_COLS]);
                b1[j] = bfs(pk[j * N_COLS + 16]);
            }
            acc0 = __builtin_amdgcn_mfma_f32_16x16x32_bf16(a, b0, acc0, 0, 0, 0);
            acc1 = __builtin_amdgcn_mfma_f32_16x16x32_bf16(a, b1, acc1, 0, 0, 0);
        }

        // cross-wave reduce: red[wave][lane][0..3]=acc0, [4..7]=acc1
        const int ro = (wave * 64 + l) * 8;
        *(f32x4*)(red + ro)     = acc0;
        *(f32x4*)(red + ro + 4) = acc1;
        __syncthreads();

        // thread sums one float2 (elements e, e+1) over the 4 waves, stores f16.
        const int e = tid * 2;
        const int le = e >> 3, j0 = e & 7;
        float2 s = make_float2(0.f, 0.f);
        #pragma unroll
        for (int w = 0; w < 4; ++w) {
            float2 v = *(const float2*)(red + w * 512 + e);
            s.x += v.x; s.y += v.y;
        }
        const int row = mBase + (le >> 4) * 4 + (j0 & 3);
        const int col = nBase + (le & 15) + (j0 >> 2) * 16;
        act_h[row * N_COLS + col]       = __float2half(s.x);   // RNE, same as R10
        act_h[(row + 1) * N_COLS + col] = __float2half(s.y);
    }

    // publish: all waves' act_h stores drained at the barrier (vmcnt0 before s_barrier)
    __syncthreads();
    if (tid == 0) {
        __builtin_amdgcn_fence(__ATOMIC_RELEASE, "");   // system: L2 writeback
        __hip_atomic_fetch_add(&g_done[bid >> 5], 1ULL,
                               __ATOMIC_RELAXED, __HIP_MEMORY_SCOPE_SYSTEM);
    }

    // ---------------- wait for own group's col-tile (throttled, bounded) ----------------
    const int k = bid >> 4;                  // 0..49
    const int chunk = bid & 15;              // 0..15
    const int nc = bid >> 5;                 // own col-tile == the one holding cols of k
    if (tid == 0) {
        for (int it = 0; it < 3000000; ++it) {   // bounded: loud-wrong, never hangs
            if (__hip_atomic_load(&g_done[nc], __ATOMIC_RELAXED,
                                  __HIP_MEMORY_SCOPE_SYSTEM) >= target) break;
            __builtin_amdgcn_s_sleep(2);
        }
    }
    __syncthreads();
    __builtin_amdgcn_fence(__ATOMIC_ACQUIRE, "");  // system: invalidate caches

    // ---------------- consume: pairwise L1 + exp-sum (R10's proven body) ----------------
    // LDS: row b as 4 half4 (uint2) slots; logical slot s stored at s ^ ((s>>6)&15).
    uint2* Ah4 = (uint2*)Sh;   // 16 KB
    {
        const __half* base = act_h + k * DK;
        #pragma unroll
        for (int i = 0; i < 8; ++i) {
            int idx = tid + i * 256;       // logical half4 slot 0..2047
            int b = idx >> 2, d4 = idx & 3;
            uint2 u = *(const uint2*)(base + b * N_COLS + d4 * 4);   // 8B-aligned
            Ah4[idx ^ ((idx >> 6) & 15)] = u;
        }
    }
    __syncthreads();

    const int rt = tid >> 5;           // 0..7 -> 4 rows each
    const int q = tid & 31;            // 0..31 -> 16 b2 each
    const int row0 = chunk * 32 + rt * 4;

    __half2 m[4][8];
    #pragma unroll
    for (int r = 0; r < 4; ++r) {
        int gr = row0 + r;
        int xr = (gr >> 4) & 15;
        #pragma unroll
        for (int j = 0; j < 4; ++j) {
            uint2 u = Ah4[(gr * 4 + j) ^ xr];
            m[r][2 * j]     = __builtin_bit_cast(__half2, u.x);
            m[r][2 * j + 1] = __builtin_bit_cast(__half2, u.y);
        }
    }

    const uint2* bq = Ah4 + q * 64;    // 16 b2 x 4 slots
    const int xm = q & 15;

    float acc[4] = {0.f, 0.f, 0.f, 0.f};
    #pragma unroll 4
    for (int i = 0; i < 16; ++i) {
        __half2 v[8];
        #pragma unroll
        for (int j = 0; j < 4; ++j) {
            uint2 u = bq[(i * 4 + j) ^ xm];
            v[2 * j]     = __builtin_bit_cast(__half2, u.x);
            v[2 * j + 1] = __builtin_bit_cast(__half2, u.y);
        }
        #pragma unroll
        for (int r = 0; r < 4; ++r) {
            __half2 s = __habs2(__hsub2(m[r][0], v[0]));
            #pragma unroll
            for (int jj = 1; jj < 8; ++jj)
                s = __hadd2(s, __habs2(__hsub2(m[r][jj], v[jj])));
            float2 f = __half22float2(s);
            acc[r] += EXP2F((f.x + f.y) * -1.4426950408889634f);
        }
    }

    #pragma unroll
    for (int r = 0; r < 4; ++r) {
        acc[r] += __shfl_xor(acc[r], 1);
        acc[r] += __shfl_xor(acc[r], 2);
        acc[r] += __shfl_xor(acc[r], 4);
        acc[r] += __shfl_xor(acc[r], 8);
        acc[r] += __shfl_xor(acc[r], 16);
    }
    if (q == 0) {
        #pragma unroll
        for (int r = 0; r < 4; ++r)
            out[(row0 + r) * OUT_COLS + F_IN + k] = acc[r];
    }
}

extern "C" void kernel_launch(void* const* d_in, const int* in_sizes, int n_in,
                              void* d_out, int out_size, void* d_ws, size_t ws_size,
                              hipStream_t stream) {
    const float* x = (const float*)d_in[0];   // (512, 512) fp32
    const float* W = (const float*)d_in[1];   // (512, 800) fp32
    float* out = (float*)d_out;               // (512, 562) fp32
    __half* act_h = (__half*)d_ws;            // (512, 800) f16 scratch (800 KB)

    fused_kernel<<<dim3(NBLOCKS), dim3(256), 0, stream>>>(x, W, act_h, out);
}

// Round 12
// 30.484 us; speedup vs baseline: 3.6005x; 3.6005x over previous
//
#include <hip/hip_runtime.h>
#include <hip/hip_bf16.h>
#include <hip/hip_fp16.h>

// MiniBatchDiscrimination: out = concat([x, sum_b2 exp(-L1(act_b, act_b2))], axis=1)
// B=512, F=512, K=50, D=16.  act = x @ W : (512, 800).
// Round 12: REVERT to R10 (best verified: 30.4 us, absmax 0.0078125).
// Final structure: two dispatches.
//  - GEMM: bf16 MFMA, K split over 4 waves, f16 act store, x-copy folded in.
//  - Pairwise: packed-f16 L1+exp, 4 rows/thread, XOR-swizzled LDS — at VALU floor.
// Fusion (4 designs) and symmetric-halving both empirically rejected; the
// remaining ~25 us is launch/graph + one dispatch boundary, outside kernel code.

#define B_ROWS 512
#define F_IN   512
#define NK     50
#define DK     16
#define N_COLS (NK * DK)      // 800
#define OUT_COLS (F_IN + NK)  // 562

#if __has_builtin(__builtin_amdgcn_exp2f)
#define EXP2F __builtin_amdgcn_exp2f
#else
#define EXP2F exp2f
#endif

typedef __attribute__((ext_vector_type(8))) short bf16x8;
typedef __attribute__((ext_vector_type(4))) float f32x4;

__device__ __forceinline__ short bfs(float f) {
    __hip_bfloat16 h = __float2bfloat16(f);   // RNE; pairs fuse to v_cvt_pk_bf16_f32
    return *reinterpret_cast<short*>(&h);
}

// ---------------- GEMM: act_h[512][800] = f16( bf16(x) @ bf16(W) ), K split over 4 waves ----
// Grid (32, 25), 256 threads. Block (bx, by) -> rows bx*16..+15, cols by*32..+31.
// Wave w handles K in [w*128, +128): 4 MFMA steps; cross-wave LDS reduce.
// A frag: lane l holds x[mBase + (l&15)][kOff + 8*(l>>4) + j]
// B frag: lane l holds W[kOff + 8*(l>>4) + j][nBase + fr*16 + (l&15)]
// C/D:    col = l&15, row = (l>>4)*4 + reg   [m89 verified]
// Blocks with flat id < 128 also copy x rows into out[:, 0:512].
__global__ __launch_bounds__(256) void gemm_ksplit_kernel(const float* __restrict__ x,
                                                          const float* __restrict__ W,
                                                          __half* __restrict__ act_h,
                                                          float* __restrict__ out) {
    __shared__ float red[4 * 64 * 8];   // 8 KB: [wave][lane][8]

    const int tid = threadIdx.x;
    const int wave = tid >> 6, l = tid & 63;
    const int bid = blockIdx.y * 32 + blockIdx.x;   // 0..799

    // x passthrough copy on 128 blocks (2 float4 per thread)
    if (bid < 128) {
        #pragma unroll
        for (int i = 0; i < 2; ++i) {
            int gid = bid * 512 + i * 256 + tid;    // 0..65535
            int row = gid >> 7, c4 = gid & 127;
            float4 v = ((const float4*)x)[gid];
            float* o = out + row * OUT_COLS + c4 * 4;   // 8B-aligned (562 even)
            *(float2*)o = make_float2(v.x, v.y);
            *(float2*)(o + 2) = make_float2(v.z, v.w);
        }
    }

    const int mBase = blockIdx.x * 16;
    const int nBase = blockIdx.y * 32;
    const int rc = l & 15, kg = l >> 4;

    const float* pa = x + (mBase + rc) * F_IN + wave * 128 + kg * 8;
    const float* pb = W + (wave * 128 + kg * 8) * N_COLS + nBase + rc;

    f32x4 acc0 = {0.f, 0.f, 0.f, 0.f};
    f32x4 acc1 = {0.f, 0.f, 0.f, 0.f};

    #pragma unroll
    for (int ks = 0; ks < 4; ++ks) {
        float4 a0 = *(const float4*)(pa + ks * 32);
        float4 a1 = *(const float4*)(pa + ks * 32 + 4);
        bf16x8 a;
        a[0] = bfs(a0.x); a[1] = bfs(a0.y); a[2] = bfs(a0.z); a[3] = bfs(a0.w);
        a[4] = bfs(a1.x); a[5] = bfs(a1.y); a[6] = bfs(a1.z); a[7] = bfs(a1.w);

        const float* pk = pb + (ks * 32) * N_COLS;
        bf16x8 b0, b1;
        #pragma unroll
        for (int j = 0; j < 8; ++j) {
            b0[j] = bfs(pk[j * N_COLS]);
            b1[j] = bfs(pk[j * N_COLS + 16]);
        }
        acc0 = __builtin_amdgcn_mfma_f32_16x16x32_bf16(a, b0, acc0, 0, 0, 0);
        acc1 = __builtin_amdgcn_mfma_f32_16x16x32_bf16(a, b1, acc1, 0, 0, 0);
    }

    // cross-wave reduce: red[wave][lane][0..3]=acc0, [4..7]=acc1
    const int ro = (wave * 64 + l) * 8;
    *(f32x4*)(red + ro)     = acc0;
    *(f32x4*)(red + ro + 4) = acc1;
    __syncthreads();

    // thread sums one float2 (elements e, e+1) over the 4 waves, stores f16.
    // e = 2*tid: le = e>>3 (lane), j0 = e&7; j<4 -> acc0[j] (fr=0), j>=4 -> acc1 (fr=1).
    // elements e, e+1 are rows (j0&3), (j0&3)+1 at the same column.
    {
        const int e = tid * 2;
        const int le = e >> 3, j0 = e & 7;
        float2 s = make_float2(0.f, 0.f);
        #pragma unroll
        for (int w = 0; w < 4; ++w) {
            float2 v = *(const float2*)(red + w * 512 + e);
            s.x += v.x; s.y += v.y;
        }
        const int row = mBase + (le >> 4) * 4 + (j0 & 3);
        const int col = nBase + (le & 15) + (j0 >> 2) * 16;
        act_h[row * N_COLS + col]       = __float2half(s.x);   // RNE
        act_h[(row + 1) * N_COLS + col] = __float2half(s.y);
    }
}

// ---------------- Pairwise L1 + exp-sum, packed f16, 4 rows/thread ----------------
// Grid (50, 16): block = (kernel k, 32-row chunk). 256 threads = 8 row-threads x 32 q.
// LDS: row b as 4 half4 (uint2) slots; logical slot s = b*4 + j stored at s ^ ((s>>6)&15)
// so q-group reads (stride 64 slots = 512B) spread across all 16 bank-pairs.
__global__ __launch_bounds__(256) void pairwise_h2_kernel(const __half* __restrict__ act_h,
                                                          float* __restrict__ out) {
    const int k = blockIdx.x;          // 0..49
    const int chunk = blockIdx.y;      // 0..15
    __shared__ uint2 Ah4[B_ROWS * 4];  // 16 KB, swizzled half4 slots

    const int tid = threadIdx.x;
    const __half* base = act_h + k * DK;
    #pragma unroll
    for (int i = 0; i < 8; ++i) {
        int idx = tid + i * 256;       // logical half4 slot 0..2047
        int b = idx >> 2, d4 = idx & 3;
        uint2 u = *(const uint2*)(base + b * N_COLS + d4 * 4);   // 8B-aligned
        Ah4[idx ^ ((idx >> 6) & 15)] = u;
    }
    __syncthreads();

    const int rt = tid >> 5;           // 0..7 -> 4 rows each
    const int q = tid & 31;            // 0..31 -> 16 b2 each
    const int row0 = chunk * 32 + rt * 4;

    // 4 m-rows in registers: 8 half2 per row
    __half2 m[4][8];
    #pragma unroll
    for (int r = 0; r < 4; ++r) {
        int gr = row0 + r;
        int xr = (gr >> 4) & 15;
        #pragma unroll
        for (int j = 0; j < 4; ++j) {
            uint2 u = Ah4[(gr * 4 + j) ^ xr];
            m[r][2 * j]     = __builtin_bit_cast(__half2, u.x);
            m[r][2 * j + 1] = __builtin_bit_cast(__half2, u.y);
        }
    }

    const uint2* bq = Ah4 + q * 64;    // 16 b2 x 4 slots
    const int xm = q & 15;

    float acc[4] = {0.f, 0.f, 0.f, 0.f};
    #pragma unroll 4
    for (int i = 0; i < 16; ++i) {
        __half2 v[8];
        #pragma unroll
        for (int j = 0; j < 4; ++j) {
            uint2 u = bq[(i * 4 + j) ^ xm];
            v[2 * j]     = __builtin_bit_cast(__half2, u.x);
            v[2 * j + 1] = __builtin_bit_cast(__half2, u.y);
        }
        #pragma unroll
        for (int r = 0; r < 4; ++r) {
            __half2 s = __habs2(__hsub2(m[r][0], v[0]));
            #pragma unroll
            for (int jj = 1; jj < 8; ++jj)
                s = __hadd2(s, __habs2(__hsub2(m[r][jj], v[jj])));
            float2 f = __half22float2(s);
            acc[r] += EXP2F((f.x + f.y) * -1.4426950408889634f);
        }
    }

    #pragma unroll
    for (int r = 0; r < 4; ++r) {
        acc[r] += __shfl_xor(acc[r], 1);
        acc[r] += __shfl_xor(acc[r], 2);
        acc[r] += __shfl_xor(acc[r], 4);
        acc[r] += __shfl_xor(acc[r], 8);
        acc[r] += __shfl_xor(acc[r], 16);
    }
    if (q == 0) {
        #pragma unroll
        for (int r = 0; r < 4; ++r)
            out[(row0 + r) * OUT_COLS + F_IN + k] = acc[r];
    }
}

extern "C" void kernel_launch(void* const* d_in, const int* in_sizes, int n_in,
                              void* d_out, int out_size, void* d_ws, size_t ws_size,
                              hipStream_t stream) {
    const float* x = (const float*)d_in[0];   // (512, 512) fp32
    const float* W = (const float*)d_in[1];   // (512, 800) fp32
    float* out = (float*)d_out;               // (512, 562) fp32
    __half* act_h = (__half*)d_ws;            // (512, 800) f16 scratch (800 KB)

    gemm_ksplit_kernel<<<dim3(32, 25), dim3(256), 0, stream>>>(x, W, act_h, out);
    pairwise_h2_kernel<<<dim3(50, 16), dim3(256), 0, stream>>>(act_h, out);
}